// Round 24
// baseline (224.796 us; speedup 1.0000x reference)
//
#include <hip/hip_runtime.h>
#include <math.h>

#define N_NODES 50000
#define N_EDGES 1600000
#define IN_CH   512
#define OUT_CH  48
#define XW_LD   64                   // xw row stride in ushorts -> 128B, one cache line
#define N_TILES (N_NODES / 16)       // 3125 row-tiles, exact

#define BSHIFT  6                    // 64 nodes per bucket
#define BNODES  64
#define NB      ((N_NODES + BNODES - 1) / BNODES)   // 782 buckets
#define ETILE   4096                 // edges per bin block (391 blocks)
#define CAP     2816                 // max edges per bucket handled by sort (mean 2046)
#define CHUNK   128                  // edges per wave in seg_aggregate (divides N_EDGES)

#define BFRAG_SHORTS (16 * 3 * 64 * 8)   // 24576 shorts = 48 KB fragment image of B

#define PREP_BLOCKS 24               // 6144 threads / 256
#define HIST_BLOCKS 256
#define GEMMB_BLOCKS ((N_TILES + 7) / 8)            // 391 (8 tiles per 512-thr block)
#define BIN_BLOCKS   ((N_EDGES + ETILE - 1) / ETILE) // 391

typedef __attribute__((ext_vector_type(8))) short bf16x8;
typedef __attribute__((ext_vector_type(4))) float f32x4;

// fp32 -> bf16 (round-to-nearest-even), branch-free
static __device__ inline short f2bf(float x) {
    union { float f; unsigned u; } in; in.f = x;
    unsigned r = in.u + 0x7fffu + ((in.u >> 16) & 1u);
    return (short)(r >> 16);
}
static __device__ inline float bf2f(unsigned v16) {
    union { unsigned u; float f; } o; o.u = v16 << 16; return o.f;
}

// ---------------- Kernel A (merged): prep_bfrag blocks + hist blocks ----------------
static __device__ void prep_body(const float* __restrict__ w,
                                 unsigned short* __restrict__ wfrag) {
    int i = blockIdx.x * 256 + threadIdx.x;              // one float4 per thread
    if (i >= IN_CH * OUT_CH / 4) return;
    int flat = i * 4;
    int k   = flat / OUT_CH;
    int col = flat % OUT_CH;
    float4 v = *reinterpret_cast<const float4*>(w + flat);
    int s = k >> 5, j = k & 7, q = (k >> 3) & 3;
    float vv[4] = {v.x, v.y, v.z, v.w};
    #pragma unroll
    for (int c = 0; c < 4; ++c) {
        int cc = col + c;
        int t  = cc >> 4;
        int ln = (cc & 15) | (q << 4);
        wfrag[((s * 3 + t) * 64 + ln) * 8 + j] = (unsigned short)f2bf(vv[c]);
    }
}

__global__ __launch_bounds__(256) void prep_hist(const float* __restrict__ w,
                                                 unsigned short* __restrict__ wfrag,
                                                 const int* __restrict__ dst,
                                                 int* __restrict__ counts) {
    __shared__ int hc[NB];
    if (blockIdx.x < PREP_BLOCKS) { prep_body(w, wfrag); return; }
    int bid = blockIdx.x - PREP_BLOCKS;
    for (int i = threadIdx.x; i < NB; i += 256) hc[i] = 0;
    __syncthreads();
    for (int e = bid * 256 + threadIdx.x; e < N_EDGES; e += HIST_BLOCKS * 256)
        atomicAdd(&hc[dst[e] >> BSHIFT], 1);
    __syncthreads();
    for (int i = threadIdx.x; i < NB; i += 256)
        if (hc[i]) atomicAdd(&counts[i], hc[i]);
}

// ---------------- Kernel: exclusive scan over NB buckets (1 block, 2/thread) ----------------
__global__ __launch_bounds__(1024) void bucket_scan(const int* __restrict__ counts,
                                                    int* __restrict__ base,
                                                    int* __restrict__ cursor) {
    __shared__ int sdata[1024];
    int t = threadIdx.x;
    int i0 = 2 * t, i1 = 2 * t + 1;
    int v0 = (i0 < NB) ? counts[i0] : 0;
    int v1 = (i1 < NB) ? counts[i1] : 0;
    int s = v0 + v1;
    sdata[t] = s;
    __syncthreads();
    for (int d = 1; d < 1024; d <<= 1) {
        int x = (t >= d) ? sdata[t - d] : 0;
        __syncthreads();
        sdata[t] += x;
        __syncthreads();
    }
    int excl = sdata[t] - s;
    if (i0 < NB) { base[i0] = excl;      cursor[i0] = excl; }
    if (i1 < NB) { base[i1] = excl + v0; cursor[i1] = excl + v0; }
}

// ---------------- Kernel B (merged): gemm blocks (8 tiles, 512 thr) + bin blocks ----------------
static __device__ void gemm_body512(char* smem, const float* __restrict__ f,
                                    const unsigned short* __restrict__ wfrag,
                                    unsigned short* __restrict__ xw) {
    short* sBl = reinterpret_cast<short*>(smem);

    int tid  = threadIdx.x;
    int lane = tid & 63;
    int wid  = tid >> 6;                                 // 8 waves

    {
        const uint4* gw = reinterpret_cast<const uint4*>(wfrag);
        uint4*       sw = reinterpret_cast<uint4*>(smem);
        #pragma unroll
        for (int i = 0; i < BFRAG_SHORTS / 8 / 512; ++i)   // 6 iterations
            sw[i * 512 + tid] = gw[i * 512 + tid];
    }
    __syncthreads();

    int tile = blockIdx.x * 8 + wid;
    if (tile >= N_TILES) return;

    const bf16x8* sB = reinterpret_cast<const bf16x8*>(sBl);

    int row = tile * 16 + (lane & 15);
    const float* fp = f + (size_t)row * IN_CH + ((lane >> 4) << 3);

    f32x4 acc0 = {0.f, 0.f, 0.f, 0.f};
    f32x4 acc1 = {0.f, 0.f, 0.f, 0.f};
    f32x4 acc2 = {0.f, 0.f, 0.f, 0.f};

    float4 a0[2], a1[2];
    a0[0] = *reinterpret_cast<const float4*>(fp);
    a1[0] = *reinterpret_cast<const float4*>(fp + 4);

    #pragma unroll
    for (int s = 0; s < 16; ++s) {
        const int cb = s & 1, nb = cb ^ 1;
        if (s + 1 < 16) {                                  // prefetch next K-step
            a0[nb] = *reinterpret_cast<const float4*>(fp + (s + 1) * 32);
            a1[nb] = *reinterpret_cast<const float4*>(fp + (s + 1) * 32 + 4);
        }
        bf16x8 a;
        a[0] = f2bf(a0[cb].x); a[1] = f2bf(a0[cb].y);
        a[2] = f2bf(a0[cb].z); a[3] = f2bf(a0[cb].w);
        a[4] = f2bf(a1[cb].x); a[5] = f2bf(a1[cb].y);
        a[6] = f2bf(a1[cb].z); a[7] = f2bf(a1[cb].w);
        bf16x8 b0 = sB[(s * 3 + 0) * 64 + lane];
        bf16x8 b1 = sB[(s * 3 + 1) * 64 + lane];
        bf16x8 b2 = sB[(s * 3 + 2) * 64 + lane];
        acc0 = __builtin_amdgcn_mfma_f32_16x16x32_bf16(a, b0, acc0, 0, 0, 0);
        acc1 = __builtin_amdgcn_mfma_f32_16x16x32_bf16(a, b1, acc1, 0, 0, 0);
        acc2 = __builtin_amdgcn_mfma_f32_16x16x32_bf16(a, b2, acc2, 0, 0, 0);
    }

    unsigned short* orow = xw + (size_t)tile * 16 * XW_LD;
    int c  = lane & 15;
    int r0 = (lane >> 4) * 4;
    #pragma unroll
    for (int r = 0; r < 4; ++r) {
        orow[(size_t)(r0 + r) * XW_LD +  0 + c] = (unsigned short)f2bf(acc0[r]);
        orow[(size_t)(r0 + r) * XW_LD + 16 + c] = (unsigned short)f2bf(acc1[r]);
        orow[(size_t)(r0 + r) * XW_LD + 32 + c] = (unsigned short)f2bf(acc2[r]);
    }
}

static __device__ void bin_body(char* smem, int bid, const int* __restrict__ src,
                                const int* __restrict__ dst, const float* __restrict__ ew,
                                int* __restrict__ cursor, int2* __restrict__ epack) {
    int*   hist  = reinterpret_cast<int*>(smem);
    int*   loff  = reinterpret_cast<int*>(smem + 3200);
    int*   gbase = reinterpret_cast<int*>(smem + 6400);
    int*   ssum  = reinterpret_cast<int*>(smem + 9600);
    int2*  buf   = reinterpret_cast<int2*>(smem + 11648);
    short* bkt   = reinterpret_cast<short*>(smem + 44416);

    int tid = threadIdx.x;
    int tileStart = bid * ETILE;
    int tileN = N_EDGES - tileStart; if (tileN > ETILE) tileN = ETILE;

    for (int i = tid; i < NB; i += 512) hist[i] = 0;
    __syncthreads();

    int rank[ETILE / 512];
    int dreg[ETILE / 512];
    #pragma unroll
    for (int k = 0; k < ETILE / 512; ++k) {
        int e = tileStart + k * 512 + tid;
        dreg[k] = (e < N_EDGES) ? dst[e] : 0;
        rank[k] = (e < N_EDGES) ? atomicAdd(&hist[dreg[k] >> BSHIFT], 1) : 0;
    }
    __syncthreads();

    for (int i = tid; i < NB; i += 512) {
        int c = hist[i];
        gbase[i] = c ? atomicAdd(&cursor[i], c) : 0;
    }

    int a0 = (2 * tid     < NB) ? hist[2 * tid]     : 0;
    int a1 = (2 * tid + 1 < NB) ? hist[2 * tid + 1] : 0;
    ssum[tid] = a0 + a1;
    __syncthreads();
    for (int d = 1; d < 512; d <<= 1) {
        int x = (tid >= d) ? ssum[tid - d] : 0;
        __syncthreads();
        ssum[tid] += x;
        __syncthreads();
    }
    int excl = ssum[tid] - (a0 + a1);
    if (2 * tid     < NB) loff[2 * tid]     = excl;
    if (2 * tid + 1 < NB) loff[2 * tid + 1] = excl + a0;
    __syncthreads();

    #pragma unroll
    for (int k = 0; k < ETILE / 512; ++k) {
        int e = tileStart + k * 512 + tid;
        if (e < N_EDGES) {
            int d = dreg[k];
            int b = d >> BSHIFT;
            int slot = loff[b] + rank[k];
            int2 p;
            p.x = (src[e] & 0xFFFF) | (d << 16);   // src 16b | full dst 16b
            p.y = __float_as_int(ew[e]);
            buf[slot] = p;
            bkt[slot] = (short)b;
        }
    }
    __syncthreads();

    for (int idx = tid; idx < tileN; idx += 512) {
        int b = bkt[idx];
        epack[gbase[b] + idx - loff[b]] = buf[idx];
    }
}

__global__ __launch_bounds__(512) void gemm_bin(const float* __restrict__ f,
                                                const unsigned short* __restrict__ wfrag,
                                                unsigned short* __restrict__ xw,
                                                const int* __restrict__ src,
                                                const int* __restrict__ dst,
                                                const float* __restrict__ ew,
                                                int* __restrict__ cursor,
                                                int2* __restrict__ epack) {
    __shared__ __align__(16) char smem[52608];   // union: gemm 48KB | bin 51.4KB
    if (blockIdx.x < GEMMB_BLOCKS) gemm_body512(smem, f, wfrag, xw);
    else bin_body(smem, blockIdx.x - GEMMB_BLOCKS, src, dst, ew, cursor, epack);
}

// ---------------- Kernel: in-bucket sort by node (512 threads) ----------------
__global__ __launch_bounds__(512) void sort_bucket(const int* __restrict__ base,
                                                   const int* __restrict__ cursor,
                                                   int2* __restrict__ epack) {
    __shared__ int2  A[CAP];      // 22.5 KB
    __shared__ int2  B[CAP];      // 22.5 KB
    __shared__ short rk[CAP];     // 5.6 KB
    __shared__ int   hist[BNODES];
    __shared__ int   loff[BNODES];

    int b  = blockIdx.x;
    int lo = base[b], hi = cursor[b];
    int len = hi - lo;
    if (len <= 0 || len > CAP) return;   // oversize: leave unsorted (agg still correct)

    int tid = threadIdx.x;
    if (tid < BNODES) hist[tid] = 0;
    for (int i = tid; i < len; i += 512) A[i] = epack[lo + i];
    __syncthreads();

    for (int i = tid; i < len; i += 512) {
        int key = (((unsigned)A[i].x) >> 16) & (BNODES - 1);
        rk[i] = (short)atomicAdd(&hist[key], 1);
    }
    __syncthreads();

    if (tid < BNODES) {           // wave 0: exclusive scan of 64 counters
        int v = hist[tid];
        int s = v;
        #pragma unroll
        for (int d = 1; d < 64; d <<= 1) {
            int t = __shfl_up(s, d);
            if (tid >= d) s += t;
        }
        loff[tid] = s - v;
    }
    __syncthreads();

    for (int i = tid; i < len; i += 512) {
        int key = (((unsigned)A[i].x) >> 16) & (BNODES - 1);
        B[loff[key] + rk[i]] = A[i];
    }
    __syncthreads();

    for (int i = tid; i < len; i += 512) epack[lo + i] = B[i];
}

// ---------------- Kernel: segmented reduction over sorted edges ----------------
// One wave per 128-edge chunk, FOUR independent quarter-wave streams:
// quarter q = lane>>4 processes edges base+4t+q (t=0..31); cq = lane&15 is the
// channel-quad index (cq<12 real). One dwordx2 gather = 4 bf16 channels, one
// instruction fetches 4 edges = 4 cache lines; 4 batches of 8 steps,
// double-buffered (compile-time indices). QUAD-SPLIT accumulation layout:
// channel c lives at row position (c&3)*12 + (c>>2) -> each of the 4 flush
// atomics writes 12 CONSECUTIVE floats.
__global__ __launch_bounds__(512) void seg_aggregate(const int2* __restrict__ epack,
                                                     const unsigned short* __restrict__ xw,
                                                     float* __restrict__ out) {
    int wv   = (blockIdx.x * blockDim.x + threadIdx.x) >> 6;
    int lane = threadIdx.x & 63;
    int base = wv * CHUNK;
    if (base >= N_EDGES) return;          // CHUNK divides N_EDGES exactly
    int q  = lane >> 4;                   // quarter: edges 4t+q
    int cq = lane & 15;                   // channel quad (cq<12 real, rest pad)
    bool act = (cq < 12);

    int2 E0 = epack[base + lane];
    int2 E1 = epack[base + 64 + lane];

    float a0 = 0.f, a1 = 0.f, a2 = 0.f, a3 = 0.f;
    int cur = ((unsigned)__shfl(E0.x, q)) >> 16;

    int px[2][8]; float pw[2][8]; uint2 u[2][8];

    #pragma unroll
    for (int k = 0; k < 8; ++k) {
        int idx = ((4 * k) & 63) | q;     // edge 4k+q (k<16 -> E0)
        px[0][k] = __shfl(E0.x, idx);
        pw[0][k] = __int_as_float(__shfl(E0.y, idx));
    }
    #pragma unroll
    for (int k = 0; k < 8; ++k)
        u[0][k] = *reinterpret_cast<const uint2*>(
            xw + (size_t)(px[0][k] & 0xFFFF) * XW_LD + (cq << 2));

    #pragma unroll
    for (int j = 0; j < 4; ++j) {         // 4 batches x 8 steps = 32 steps (128 edges)
        const int cb = j & 1, nb = cb ^ 1;
        if (j + 1 < 4) {
            #pragma unroll
            for (int k = 0; k < 8; ++k) {
                int t  = (j + 1) * 8 + k;
                int sx = (t < 16) ? E0.x : E1.x;
                int sy = (t < 16) ? E0.y : E1.y;
                int idx = ((4 * t) & 63) | q;
                px[nb][k] = __shfl(sx, idx);
                pw[nb][k] = __int_as_float(__shfl(sy, idx));
            }
            #pragma unroll
            for (int k = 0; k < 8; ++k)
                u[nb][k] = *reinterpret_cast<const uint2*>(
                    xw + (size_t)(px[nb][k] & 0xFFFF) * XW_LD + (cq << 2));
        }
        #pragma unroll
        for (int k = 0; k < 8; ++k) {
            int node = ((unsigned)px[cb][k]) >> 16;
            if (node != cur) {            // uniform within each quarter
                if (act) {
                    atomicAdd(&out[(size_t)cur * OUT_CH +  0 + cq], a0);
                    atomicAdd(&out[(size_t)cur * OUT_CH + 12 + cq], a1);
                    atomicAdd(&out[(size_t)cur * OUT_CH + 24 + cq], a2);
                    atomicAdd(&out[(size_t)cur * OUT_CH + 36 + cq], a3);
                }
                a0 = 0.f; a1 = 0.f; a2 = 0.f; a3 = 0.f; cur = node;
            }
            float wf = pw[cb][k];
            uint2 uu = u[cb][k];
            a0 = fmaf(wf, bf2f(uu.x & 0xFFFFu), a0);
            a1 = fmaf(wf, bf2f(uu.x >> 16), a1);
            a2 = fmaf(wf, bf2f(uu.y & 0xFFFFu), a2);
            a3 = fmaf(wf, bf2f(uu.y >> 16), a3);
        }
    }

    if (act) {
        atomicAdd(&out[(size_t)cur * OUT_CH +  0 + cq], a0);
        atomicAdd(&out[(size_t)cur * OUT_CH + 12 + cq], a1);
        atomicAdd(&out[(size_t)cur * OUT_CH + 24 + cq], a2);
        atomicAdd(&out[(size_t)cur * OUT_CH + 36 + cq], a3);
    }
}

// ---------------- Kernel: bias + log-softmax, quad-split -> standard layout ----------------
// z is in quad-split layout: channel c lives at position (c&3)*12 + (c>>2).
// Softmax is order-independent; write standard layout.
__global__ __launch_bounds__(256) void lsm_rows(float* __restrict__ z,
                                                const float* __restrict__ bias) {
    int node = (blockIdx.x * blockDim.x + threadIdx.x) >> 6;
    int lane = threadIdx.x & 63;
    if (node >= N_NODES) return;
    bool ch = (lane < OUT_CH);

    int pos = (lane & 3) * 12 + (lane >> 2);
    float v = ch ? (z[(size_t)node * OUT_CH + pos] + bias[lane]) : -INFINITY;
    float m = v;
    #pragma unroll
    for (int d = 32; d >= 1; d >>= 1) m = fmaxf(m, __shfl_xor(m, d));
    float e = ch ? expf(v - m) : 0.f;
    float s = e;
    #pragma unroll
    for (int d = 32; d >= 1; d >>= 1) s += __shfl_xor(s, d);
    float lse = m + logf(s);
    if (ch) z[(size_t)node * OUT_CH + lane] = v - lse;
}

extern "C" void kernel_launch(void* const* d_in, const int* in_sizes, int n_in,
                              void* d_out, int out_size, void* d_ws, size_t ws_size,
                              hipStream_t stream) {
    const int*   edge_index = (const int*)d_in[0];
    const float* features   = (const float*)d_in[1];
    const float* eweights   = (const float*)d_in[2];
    const float* weight     = (const float*)d_in[3];
    const float* bias       = (const float*)d_in[4];

    const int* src = edge_index;            // edge_index[0, :]
    const int* dst = edge_index + N_EDGES;  // edge_index[1, :]

    float* out = (float*)d_out;

    // Workspace layout (bytes):
    //   xw (bf16, LD=64) @ 0 : 50000*64*2 = 6,400,000
    //   counts  @ 9,600,000 : NB*4
    //   base    @ 9,616,000 : NB*4
    //   cursor  @ 9,632,000 : NB*4
    //   epack   @ 9,648,000 : 12,800,000   (ends 22,448,000)
    //   wfrag   @ 22,448,000 : 49,152
    char* ws = (char*)d_ws;
    unsigned short* xw    = (unsigned short*)(ws + 0);
    int*   counts = (int*)  (ws + 9600000);
    int*   base   = (int*)  (ws + 9616000);
    int*   cursor = (int*)  (ws + 9632000);
    int2*  epack  = (int2*) (ws + 9648000);
    unsigned short* wfrag = (unsigned short*)(ws + 22448000);

    hipMemsetAsync(counts, 0, NB * sizeof(int), stream);
    hipMemsetAsync(d_out, 0, (size_t)N_NODES * OUT_CH * sizeof(float), stream);

    // A) prep_bfrag and dst-histogram, concurrent in one launch
    prep_hist<<<PREP_BLOCKS + HIST_BLOCKS, 256, 0, stream>>>(weight, wfrag, dst, counts);

    // B) scan, then gemm (bf16 MFMA) and bucket binning concurrent in one launch
    bucket_scan<<<1, 1024, 0, stream>>>(counts, base, cursor);
    gemm_bin<<<GEMMB_BLOCKS + BIN_BLOCKS, 512, 0, stream>>>(features, wfrag, xw,
                                                            src, dst, eweights,
                                                            cursor, epack);

    // C) in-bucket sort
    sort_bucket<<<NB, 512, 0, stream>>>(base, cursor, epack);

    // D) segmented reduction (wave per 128-edge chunk, quarter-wave streams)
    {
        int nWaves  = N_EDGES / CHUNK;                 // 12500
        int nBlocks = (nWaves + 7) / 8;                // 1563
        seg_aggregate<<<nBlocks, 512, 0, stream>>>(epack, xw, out);
    }
    // E) bias + log-softmax (reads quad-split, writes standard)
    lsm_rows<<<(N_NODES + 3) / 4, 256, 0, stream>>>(out, bias);
}

// Round 25
// 127.396 us; speedup vs baseline: 1.7645x; 1.7645x over previous
//
#include <hip/hip_runtime.h>
#include <math.h>

#define N_NODES 50000
#define N_EDGES 1600000
#define IN_CH   512
#define OUT_CH  48
#define XW_LD   64                   // xw row stride in ushorts -> 128B, one cache line
#define N_TILES (N_NODES / 16)       // 3125 row-tiles, exact

#define BSHIFT  6                    // 64 nodes per bucket
#define BNODES  64
#define NB      ((N_NODES + BNODES - 1) / BNODES)   // 782 buckets
#define ETILE   4096                 // edges per bin block (391 blocks)
#define CAP     2816                 // max edges per bucket handled by sort (mean 2046)
#define CHUNK   128                  // edges per wave in seg_aggregate (divides N_EDGES)

#define BFRAG_SHORTS (16 * 3 * 64 * 8)   // 24576 shorts = 48 KB fragment image of B

#define PREP_BLOCKS 24               // 6144 threads / 256
#define HIST_BLOCKS 256
#define GEMMB_BLOCKS ((N_TILES + 7) / 8)            // 391 (8 tiles per 512-thr block)
#define BIN_BLOCKS   ((N_EDGES + ETILE - 1) / ETILE) // 391

typedef __attribute__((ext_vector_type(8))) short bf16x8;
typedef __attribute__((ext_vector_type(4))) float f32x4;

// fp32 -> bf16 (round-to-nearest-even), branch-free
static __device__ inline short f2bf(float x) {
    union { float f; unsigned u; } in; in.f = x;
    unsigned r = in.u + 0x7fffu + ((in.u >> 16) & 1u);
    return (short)(r >> 16);
}
static __device__ inline float bf2f(unsigned v16) {
    union { unsigned u; float f; } o; o.u = v16 << 16; return o.f;
}

// ---------------- Kernel A (merged): prep_bfrag blocks + hist blocks ----------------
static __device__ void prep_body(const float* __restrict__ w,
                                 unsigned short* __restrict__ wfrag) {
    int i = blockIdx.x * 256 + threadIdx.x;              // one float4 per thread
    if (i >= IN_CH * OUT_CH / 4) return;
    int flat = i * 4;
    int k   = flat / OUT_CH;
    int col = flat % OUT_CH;
    float4 v = *reinterpret_cast<const float4*>(w + flat);
    int s = k >> 5, j = k & 7, q = (k >> 3) & 3;
    float vv[4] = {v.x, v.y, v.z, v.w};
    #pragma unroll
    for (int c = 0; c < 4; ++c) {
        int cc = col + c;
        int t  = cc >> 4;
        int ln = (cc & 15) | (q << 4);
        wfrag[((s * 3 + t) * 64 + ln) * 8 + j] = (unsigned short)f2bf(vv[c]);
    }
}

__global__ __launch_bounds__(256) void prep_hist(const float* __restrict__ w,
                                                 unsigned short* __restrict__ wfrag,
                                                 const int* __restrict__ dst,
                                                 int* __restrict__ counts) {
    __shared__ int hc[NB];
    if (blockIdx.x < PREP_BLOCKS) { prep_body(w, wfrag); return; }
    int bid = blockIdx.x - PREP_BLOCKS;
    for (int i = threadIdx.x; i < NB; i += 256) hc[i] = 0;
    __syncthreads();
    for (int e = bid * 256 + threadIdx.x; e < N_EDGES; e += HIST_BLOCKS * 256)
        atomicAdd(&hc[dst[e] >> BSHIFT], 1);
    __syncthreads();
    for (int i = threadIdx.x; i < NB; i += 256)
        if (hc[i]) atomicAdd(&counts[i], hc[i]);
}

// ---------------- Kernel: exclusive scan over NB buckets (1 block, 2/thread) ----------------
__global__ __launch_bounds__(1024) void bucket_scan(const int* __restrict__ counts,
                                                    int* __restrict__ base,
                                                    int* __restrict__ cursor) {
    __shared__ int sdata[1024];
    int t = threadIdx.x;
    int i0 = 2 * t, i1 = 2 * t + 1;
    int v0 = (i0 < NB) ? counts[i0] : 0;
    int v1 = (i1 < NB) ? counts[i1] : 0;
    int s = v0 + v1;
    sdata[t] = s;
    __syncthreads();
    for (int d = 1; d < 1024; d <<= 1) {
        int x = (t >= d) ? sdata[t - d] : 0;
        __syncthreads();
        sdata[t] += x;
        __syncthreads();
    }
    int excl = sdata[t] - s;
    if (i0 < NB) { base[i0] = excl;      cursor[i0] = excl; }
    if (i1 < NB) { base[i1] = excl + v0; cursor[i1] = excl + v0; }
}

// ---------------- Kernel B (merged): gemm blocks (8 tiles, 512 thr) + bin blocks ----------------
static __device__ void gemm_body512(char* smem, const float* __restrict__ f,
                                    const unsigned short* __restrict__ wfrag,
                                    unsigned short* __restrict__ xw) {
    short* sBl = reinterpret_cast<short*>(smem);

    int tid  = threadIdx.x;
    int lane = tid & 63;
    int wid  = tid >> 6;                                 // 8 waves

    {
        const uint4* gw = reinterpret_cast<const uint4*>(wfrag);
        uint4*       sw = reinterpret_cast<uint4*>(smem);
        #pragma unroll
        for (int i = 0; i < BFRAG_SHORTS / 8 / 512; ++i)   // 6 iterations
            sw[i * 512 + tid] = gw[i * 512 + tid];
    }
    __syncthreads();

    int tile = blockIdx.x * 8 + wid;
    if (tile >= N_TILES) return;

    const bf16x8* sB = reinterpret_cast<const bf16x8*>(sBl);

    int row = tile * 16 + (lane & 15);
    const float* fp = f + (size_t)row * IN_CH + ((lane >> 4) << 3);

    f32x4 acc0 = {0.f, 0.f, 0.f, 0.f};
    f32x4 acc1 = {0.f, 0.f, 0.f, 0.f};
    f32x4 acc2 = {0.f, 0.f, 0.f, 0.f};

    float4 a0[2], a1[2];
    a0[0] = *reinterpret_cast<const float4*>(fp);
    a1[0] = *reinterpret_cast<const float4*>(fp + 4);

    #pragma unroll
    for (int s = 0; s < 16; ++s) {
        const int cb = s & 1, nb = cb ^ 1;
        if (s + 1 < 16) {                                  // prefetch next K-step
            a0[nb] = *reinterpret_cast<const float4*>(fp + (s + 1) * 32);
            a1[nb] = *reinterpret_cast<const float4*>(fp + (s + 1) * 32 + 4);
        }
        bf16x8 a;
        a[0] = f2bf(a0[cb].x); a[1] = f2bf(a0[cb].y);
        a[2] = f2bf(a0[cb].z); a[3] = f2bf(a0[cb].w);
        a[4] = f2bf(a1[cb].x); a[5] = f2bf(a1[cb].y);
        a[6] = f2bf(a1[cb].z); a[7] = f2bf(a1[cb].w);
        bf16x8 b0 = sB[(s * 3 + 0) * 64 + lane];
        bf16x8 b1 = sB[(s * 3 + 1) * 64 + lane];
        bf16x8 b2 = sB[(s * 3 + 2) * 64 + lane];
        acc0 = __builtin_amdgcn_mfma_f32_16x16x32_bf16(a, b0, acc0, 0, 0, 0);
        acc1 = __builtin_amdgcn_mfma_f32_16x16x32_bf16(a, b1, acc1, 0, 0, 0);
        acc2 = __builtin_amdgcn_mfma_f32_16x16x32_bf16(a, b2, acc2, 0, 0, 0);
    }

    unsigned short* orow = xw + (size_t)tile * 16 * XW_LD;
    int c  = lane & 15;
    int r0 = (lane >> 4) * 4;
    #pragma unroll
    for (int r = 0; r < 4; ++r) {
        orow[(size_t)(r0 + r) * XW_LD +  0 + c] = (unsigned short)f2bf(acc0[r]);
        orow[(size_t)(r0 + r) * XW_LD + 16 + c] = (unsigned short)f2bf(acc1[r]);
        orow[(size_t)(r0 + r) * XW_LD + 32 + c] = (unsigned short)f2bf(acc2[r]);
    }
}

static __device__ void bin_body(char* smem, int bid, const int* __restrict__ src,
                                const int* __restrict__ dst, const float* __restrict__ ew,
                                int* __restrict__ cursor, int2* __restrict__ epack) {
    int*   hist  = reinterpret_cast<int*>(smem);
    int*   loff  = reinterpret_cast<int*>(smem + 3200);
    int*   gbase = reinterpret_cast<int*>(smem + 6400);
    int*   ssum  = reinterpret_cast<int*>(smem + 9600);
    int2*  buf   = reinterpret_cast<int2*>(smem + 11648);
    short* bkt   = reinterpret_cast<short*>(smem + 44416);

    int tid = threadIdx.x;
    int tileStart = bid * ETILE;
    int tileN = N_EDGES - tileStart; if (tileN > ETILE) tileN = ETILE;

    for (int i = tid; i < NB; i += 512) hist[i] = 0;
    __syncthreads();

    int rank[ETILE / 512];
    int dreg[ETILE / 512];
    #pragma unroll
    for (int k = 0; k < ETILE / 512; ++k) {
        int e = tileStart + k * 512 + tid;
        dreg[k] = (e < N_EDGES) ? dst[e] : 0;
        rank[k] = (e < N_EDGES) ? atomicAdd(&hist[dreg[k] >> BSHIFT], 1) : 0;
    }
    __syncthreads();

    for (int i = tid; i < NB; i += 512) {
        int c = hist[i];
        gbase[i] = c ? atomicAdd(&cursor[i], c) : 0;
    }

    int a0 = (2 * tid     < NB) ? hist[2 * tid]     : 0;
    int a1 = (2 * tid + 1 < NB) ? hist[2 * tid + 1] : 0;
    ssum[tid] = a0 + a1;
    __syncthreads();
    for (int d = 1; d < 512; d <<= 1) {
        int x = (tid >= d) ? ssum[tid - d] : 0;
        __syncthreads();
        ssum[tid] += x;
        __syncthreads();
    }
    int excl = ssum[tid] - (a0 + a1);
    if (2 * tid     < NB) loff[2 * tid]     = excl;
    if (2 * tid + 1 < NB) loff[2 * tid + 1] = excl + a0;
    __syncthreads();

    #pragma unroll
    for (int k = 0; k < ETILE / 512; ++k) {
        int e = tileStart + k * 512 + tid;
        if (e < N_EDGES) {
            int d = dreg[k];
            int b = d >> BSHIFT;
            int slot = loff[b] + rank[k];
            int2 p;
            p.x = (src[e] & 0xFFFF) | (d << 16);   // src 16b | full dst 16b
            p.y = __float_as_int(ew[e]);
            buf[slot] = p;
            bkt[slot] = (short)b;
        }
    }
    __syncthreads();

    for (int idx = tid; idx < tileN; idx += 512) {
        int b = bkt[idx];
        epack[gbase[b] + idx - loff[b]] = buf[idx];
    }
}

__global__ __launch_bounds__(512) void gemm_bin(const float* __restrict__ f,
                                                const unsigned short* __restrict__ wfrag,
                                                unsigned short* __restrict__ xw,
                                                const int* __restrict__ src,
                                                const int* __restrict__ dst,
                                                const float* __restrict__ ew,
                                                int* __restrict__ cursor,
                                                int2* __restrict__ epack) {
    __shared__ __align__(16) char smem[52608];   // union: gemm 48KB | bin 51.4KB
    if (blockIdx.x < GEMMB_BLOCKS) gemm_body512(smem, f, wfrag, xw);
    else bin_body(smem, blockIdx.x - GEMMB_BLOCKS, src, dst, ew, cursor, epack);
}

// ---------------- Kernel: in-bucket sort by node (512 threads) ----------------
__global__ __launch_bounds__(512) void sort_bucket(const int* __restrict__ base,
                                                   const int* __restrict__ cursor,
                                                   int2* __restrict__ epack) {
    __shared__ int2  A[CAP];      // 22.5 KB
    __shared__ int2  B[CAP];      // 22.5 KB
    __shared__ short rk[CAP];     // 5.6 KB
    __shared__ int   hist[BNODES];
    __shared__ int   loff[BNODES];

    int b  = blockIdx.x;
    int lo = base[b], hi = cursor[b];
    int len = hi - lo;
    if (len <= 0 || len > CAP) return;   // oversize: leave unsorted (agg still correct)

    int tid = threadIdx.x;
    if (tid < BNODES) hist[tid] = 0;
    for (int i = tid; i < len; i += 512) A[i] = epack[lo + i];
    __syncthreads();

    for (int i = tid; i < len; i += 512) {
        int key = (((unsigned)A[i].x) >> 16) & (BNODES - 1);
        rk[i] = (short)atomicAdd(&hist[key], 1);
    }
    __syncthreads();

    if (tid < BNODES) {           // wave 0: exclusive scan of 64 counters
        int v = hist[tid];
        int s = v;
        #pragma unroll
        for (int d = 1; d < 64; d <<= 1) {
            int t = __shfl_up(s, d);
            if (tid >= d) s += t;
        }
        loff[tid] = s - v;
    }
    __syncthreads();

    for (int i = tid; i < len; i += 512) {
        int key = (((unsigned)A[i].x) >> 16) & (BNODES - 1);
        B[loff[key] + rk[i]] = A[i];
    }
    __syncthreads();

    for (int i = tid; i < len; i += 512) epack[lo + i] = B[i];
}

// ---------------- Kernel: segmented reduction over sorted edges ----------------
// One wave per 128-edge chunk, TWO independent half-wave streams; one dword
// gather = 2 bf16 channels, one line per edge; 8-deep double-buffered batches.
// PAIR-SPLIT accumulation layout: low ushort channels at row positions 0..23,
// high ushort channels at 24..47 -> each flush atomic writes 24 CONSECUTIVE
// floats.
__global__ __launch_bounds__(512) void seg_aggregate(const int2* __restrict__ epack,
                                                     const unsigned short* __restrict__ xw,
                                                     float* __restrict__ out) {
    int wv   = (blockIdx.x * blockDim.x + threadIdx.x) >> 6;
    int lane = threadIdx.x & 63;
    int base = wv * CHUNK;
    if (base >= N_EDGES) return;          // CHUNK divides N_EDGES exactly
    int h  = lane >> 5;                   // half: 0 -> even edges, 1 -> odd edges
    int cp = lane & 31;                   // channel pair (cp<24 real, rest pad)
    bool act = (cp < 24);

    int2 E0 = epack[base + lane];
    int2 E1 = epack[base + 64 + lane];

    float ax = 0.f, ay = 0.f;
    int cur = ((unsigned)__shfl(E0.x, h)) >> 16;

    int px[2][8]; float pw[2][8]; unsigned u[2][8];

    #pragma unroll
    for (int k = 0; k < 8; ++k) {
        int idx = ((2 * k) & 63) | h;
        px[0][k] = __shfl(E0.x, idx);
        pw[0][k] = __int_as_float(__shfl(E0.y, idx));
    }
    #pragma unroll
    for (int k = 0; k < 8; ++k)
        u[0][k] = *reinterpret_cast<const unsigned*>(
            xw + (size_t)(px[0][k] & 0xFFFF) * XW_LD + (cp << 1));

    #pragma unroll
    for (int j = 0; j < 8; ++j) {
        const int cb = j & 1, nb = cb ^ 1;
        if (j + 1 < 8) {
            #pragma unroll
            for (int k = 0; k < 8; ++k) {
                int t  = (j + 1) * 8 + k;
                int sx = (t < 32) ? E0.x : E1.x;
                int sy = (t < 32) ? E0.y : E1.y;
                int idx = ((2 * t) & 63) | h;
                px[nb][k] = __shfl(sx, idx);
                pw[nb][k] = __int_as_float(__shfl(sy, idx));
            }
            #pragma unroll
            for (int k = 0; k < 8; ++k)
                u[nb][k] = *reinterpret_cast<const unsigned*>(
                    xw + (size_t)(px[nb][k] & 0xFFFF) * XW_LD + (cp << 1));
        }
        #pragma unroll
        for (int k = 0; k < 8; ++k) {
            int node = ((unsigned)px[cb][k]) >> 16;
            if (node != cur) {
                if (act) {
                    atomicAdd(&out[(size_t)cur * OUT_CH + cp     ], ax);  // consecutive
                    atomicAdd(&out[(size_t)cur * OUT_CH + 24 + cp], ay);  // consecutive
                }
                ax = 0.f; ay = 0.f; cur = node;
            }
            float    wf = pw[cb][k];
            unsigned uu = u[cb][k];
            ax = fmaf(wf, bf2f(uu & 0xFFFFu), ax);
            ay = fmaf(wf, bf2f(uu >> 16), ay);
        }
    }

    if (act) {
        atomicAdd(&out[(size_t)cur * OUT_CH + cp     ], ax);
        atomicAdd(&out[(size_t)cur * OUT_CH + 24 + cp], ay);
    }
}

// ---------------- Kernel: bias + log-softmax, pair-split -> standard layout ----------------
__global__ __launch_bounds__(256) void lsm_rows(float* __restrict__ z,
                                                const float* __restrict__ bias) {
    int node = (blockIdx.x * blockDim.x + threadIdx.x) >> 6;
    int lane = threadIdx.x & 63;
    if (node >= N_NODES) return;
    bool ch = (lane < OUT_CH);

    // lane = output channel; its value lives at pair-split position:
    int pos = (lane >> 1) + 24 * (lane & 1);
    float v = ch ? (z[(size_t)node * OUT_CH + pos] + bias[lane]) : -INFINITY;
    float m = v;
    #pragma unroll
    for (int d = 32; d >= 1; d >>= 1) m = fmaxf(m, __shfl_xor(m, d));
    float e = ch ? expf(v - m) : 0.f;
    float s = e;
    #pragma unroll
    for (int d = 32; d >= 1; d >>= 1) s += __shfl_xor(s, d);
    float lse = m + logf(s);
    __syncthreads();   // intra-block: all reads of this block's rows done before writes
    if (ch) z[(size_t)node * OUT_CH + lane] = v - lse;
}

extern "C" void kernel_launch(void* const* d_in, const int* in_sizes, int n_in,
                              void* d_out, int out_size, void* d_ws, size_t ws_size,
                              hipStream_t stream) {
    const int*   edge_index = (const int*)d_in[0];
    const float* features   = (const float*)d_in[1];
    const float* eweights   = (const float*)d_in[2];
    const float* weight     = (const float*)d_in[3];
    const float* bias       = (const float*)d_in[4];

    const int* src = edge_index;            // edge_index[0, :]
    const int* dst = edge_index + N_EDGES;  // edge_index[1, :]

    float* out = (float*)d_out;

    // Workspace layout (bytes):
    //   xw (bf16, LD=64) @ 0 : 50000*64*2 = 6,400,000
    //   counts  @ 9,600,000 : NB*4
    //   base    @ 9,616,000 : NB*4
    //   cursor  @ 9,632,000 : NB*4
    //   epack   @ 9,648,000 : 12,800,000   (ends 22,448,000)
    //   wfrag   @ 22,448,000 : 49,152
    char* ws = (char*)d_ws;
    unsigned short* xw    = (unsigned short*)(ws + 0);
    int*   counts = (int*)  (ws + 9600000);
    int*   base   = (int*)  (ws + 9616000);
    int*   cursor = (int*)  (ws + 9632000);
    int2*  epack  = (int2*) (ws + 9648000);
    unsigned short* wfrag = (unsigned short*)(ws + 22448000);

    hipMemsetAsync(counts, 0, NB * sizeof(int), stream);
    hipMemsetAsync(d_out, 0, (size_t)N_NODES * OUT_CH * sizeof(float), stream);

    // A) prep_bfrag and dst-histogram, concurrent in one launch
    prep_hist<<<PREP_BLOCKS + HIST_BLOCKS, 256, 0, stream>>>(weight, wfrag, dst, counts);

    // B) scan, then gemm (bf16 MFMA) and bucket binning concurrent in one launch
    bucket_scan<<<1, 1024, 0, stream>>>(counts, base, cursor);
    gemm_bin<<<GEMMB_BLOCKS + BIN_BLOCKS, 512, 0, stream>>>(features, wfrag, xw,
                                                            src, dst, eweights,
                                                            cursor, epack);

    // C) in-bucket sort
    sort_bucket<<<NB, 512, 0, stream>>>(base, cursor, epack);

    // D) segmented reduction (wave per 128-edge chunk, pair-split atomics)
    {
        int nWaves  = N_EDGES / CHUNK;                 // 12500
        int nBlocks = (nWaves + 7) / 8;                // 1563
        seg_aggregate<<<nBlocks, 512, 0, stream>>>(epack, xw, out);
    }
    // E) bias + log-softmax (reads pair-split, writes standard)
    lsm_rows<<<(N_NODES + 3) / 4, 256, 0, stream>>>(out, bias);
}